// Round 7
// baseline (962.950 us; speedup 1.0000x reference)
//
#include <hip/hip_runtime.h>
#include <hip/hip_bf16.h>

#define T_TOK 8192
#define D_DIM 1024
#define F_DIM 4096
#define E_NUM 8
#define BM 256
#define MAX_ROWS (2 * T_TOK + E_NUM * BM)   // 18432
#define NUM_RB (MAX_ROWS / BM)              // 72

typedef __hip_bfloat16 bf16;
using bf16x8  = __attribute__((ext_vector_type(8))) __bf16;
using float4v = __attribute__((ext_vector_type(4))) float;

// async global->LDS, 16B per lane; dest = wave-uniform base + lane*16
__device__ inline void gl_lds16(const bf16* g, bf16* l) {
    __builtin_amdgcn_global_load_lds(
        (const __attribute__((address_space(1))) void*)g,
        (__attribute__((address_space(3))) void*)l, 16, 0, 0);
}

// ---- 8-phase template pieces (m201 port) ----
#define RD_A(REG, MH)                                                         \
    _Pragma("unroll") for (int m_ = 0; m_ < 4; ++m_)                          \
        af[m_] = *(const bf16x8*)&(REG)[(wr * 128 + (MH) * 64 + m_ * 16 +     \
                                         (lane & 15)) * 32 + fkk];
#define RD_B(REG)                                                             \
    _Pragma("unroll") for (int n_ = 0; n_ < 4; ++n_)                          \
        bfr[n_] = *(const bf16x8*)&(REG)[(wc * 64 + n_ * 16 +                 \
                                          (lane & 15)) * 32 + fkk];
#define BAR1()                                                                \
    asm volatile("s_barrier" ::: "memory");                                   \
    asm volatile("s_waitcnt lgkmcnt(0)" ::: "memory");                        \
    __builtin_amdgcn_sched_barrier(0);
#define MFMA16(MH)                                                            \
    __builtin_amdgcn_s_setprio(1);                                            \
    _Pragma("unroll") for (int m_ = 0; m_ < 4; ++m_)                          \
        _Pragma("unroll") for (int n_ = 0; n_ < 4; ++n_)                      \
            acc[MH][m_][n_] = __builtin_amdgcn_mfma_f32_16x16x32_bf16(        \
                af[m_], bfr[n_], acc[MH][m_][n_], 0, 0, 0);                   \
    __builtin_amdgcn_s_setprio(0);                                            \
    asm volatile("s_barrier" ::: "memory");
#define VM6 asm volatile("s_waitcnt vmcnt(6)" ::: "memory");
#define VM0 asm volatile("s_waitcnt vmcnt(0)" ::: "memory");
#define VMN

// One K-tile (BK=64) = 4 phases. Stages: P1 -> Ak1(t+1); P2/P3/P4 ->
// Bk0/Ak0/Bk1 of (t+2). Each region staged one barrier after its last read.
#define TILE(AK0, AK1, BK0, BK1, SAK1T1, SBK0T2, SAK0T2, SBK1T2, D1, D2, KO1, KO2, BVM) \
  { bf16x8 af[4], bfr[4];                                                     \
    RD_A(AK0, 0) RD_B(BK0)                                                    \
    if (D1) { stageA(SAK1T1, (KO1) + 32); }                                   \
    BAR1() MFMA16(0)                                                          \
    RD_A(AK0, 1)                                                              \
    if (D2) { stageB(SBK0T2, (KO2)); }                                        \
    BAR1() MFMA16(1)                                                          \
    RD_A(AK1, 0) RD_B(BK1)                                                    \
    if (D2) { stageA(SAK0T2, (KO2)); }                                        \
    BAR1() MFMA16(0)                                                          \
    RD_A(AK1, 1)                                                              \
    if (D2) { stageB(SBK1T2, (KO2) + 32); }                                   \
    BVM BAR1() MFMA16(1)                                                      \
  }

// ---------------- x -> bf16 ----------------
__global__ __launch_bounds__(256) void xcvt_kernel(const float* __restrict__ x,
                                                   bf16* __restrict__ xb) {
    const int i = blockIdx.x * 256 + threadIdx.x;  // over T*D/4
    float4 v = ((const float4*)x)[i];
    bf16 tmp[4];
    tmp[0] = __float2bfloat16(v.x);
    tmp[1] = __float2bfloat16(v.y);
    tmp[2] = __float2bfloat16(v.z);
    tmp[3] = __float2bfloat16(v.w);
    ((ushort4*)xb)[i] = *(const ushort4*)tmp;
}

// ------- transpose+convert: src[e][M][N] f32 -> dst[e][N][M] bf16, 64x64 tiles -------
__global__ __launch_bounds__(256) void transpose_cvt(const float* __restrict__ src,
                                                     bf16* __restrict__ dst,
                                                     int M, int N) {
    __shared__ float tile[64][65];
    const int e = blockIdx.z;
    const float* s = src + (size_t)e * M * N;
    bf16* d = dst + (size_t)e * M * N;
    const int n0 = blockIdx.x * 64, m0 = blockIdx.y * 64;
    const int tx = threadIdx.x & 15, ty = threadIdx.x >> 4;
#pragma unroll
    for (int i = 0; i < 4; ++i) {
        const int r = ty + i * 16;
        const float4 v = *(const float4*)&s[(size_t)(m0 + r) * N + n0 + tx * 4];
        tile[r][tx * 4 + 0] = v.x;
        tile[r][tx * 4 + 1] = v.y;
        tile[r][tx * 4 + 2] = v.z;
        tile[r][tx * 4 + 3] = v.w;
    }
    __syncthreads();
#pragma unroll
    for (int i = 0; i < 4; ++i) {
        const int nc = ty + i * 16;
        bf16 o[4];
#pragma unroll
        for (int j = 0; j < 4; ++j) o[j] = __float2bfloat16(tile[tx * 4 + j][nc]);
        *(ushort4*)&d[(size_t)(n0 + nc) * M + m0 + tx * 4] = *(const ushort4*)o;
    }
}

// ---------------- router: logits (fp32), top-2, softmax, counts ----------------
__global__ __launch_bounds__(256) void router_kernel(
    const float* __restrict__ x, const float* __restrict__ Wg,
    const float* __restrict__ bg, int* __restrict__ top_idx,
    float* __restrict__ top_gate, int* __restrict__ counts) {
    __shared__ float wg_s[E_NUM][D_DIM];
    for (int i = threadIdx.x; i < D_DIM * E_NUM; i += 256)
        wg_s[i & 7][i >> 3] = Wg[i];
    __syncthreads();

    const int lane = threadIdx.x & 63;
    const int t = blockIdx.x * 4 + (threadIdx.x >> 6);
    float acc[E_NUM];
#pragma unroll
    for (int e = 0; e < E_NUM; ++e) acc[e] = 0.f;
    const float* xrow = x + (size_t)t * D_DIM;
    for (int d = lane; d < D_DIM; d += 64) {
        const float xv = xrow[d];
#pragma unroll
        for (int e = 0; e < E_NUM; ++e) acc[e] += xv * wg_s[e][d];
    }
#pragma unroll
    for (int off = 32; off > 0; off >>= 1) {
#pragma unroll
        for (int e = 0; e < E_NUM; ++e) acc[e] += __shfl_xor(acc[e], off, 64);
    }
    if (lane == 0) {
        float v[E_NUM];
#pragma unroll
        for (int e = 0; e < E_NUM; ++e) v[e] = acc[e] + bg[e];
        int i0 = 0;
#pragma unroll
        for (int e = 1; e < E_NUM; ++e)
            if (v[e] > v[i0]) i0 = e;
        int i1 = -1;
#pragma unroll
        for (int e = 0; e < E_NUM; ++e) {
            if (e == i0) continue;
            if (i1 < 0 || v[e] > v[i1]) i1 = e;
        }
        const float g0 = 1.f / (1.f + expf(v[i1] - v[i0]));
        top_idx[2 * t] = i0;
        top_idx[2 * t + 1] = i1;
        top_gate[2 * t] = g0;
        top_gate[2 * t + 1] = 1.f - g0;
        atomicAdd(&counts[i0], 1);
        atomicAdd(&counts[i1], 1);
    }
}

// ---------------- padded segment offsets (pad to BM=256) ----------------
__global__ void offsets_kernel(const int* __restrict__ counts, int* __restrict__ offsets) {
    if (threadIdx.x == 0) {
        int off = 0;
#pragma unroll
        for (int e = 0; e < E_NUM; ++e) {
            offsets[e] = off;
            off += (counts[e] + BM - 1) / BM * BM;
        }
        offsets[E_NUM] = off;
    }
}

// ---------------- scatter tokens into expert segments ----------------
__global__ __launch_bounds__(256) void scatter_kernel(
    const int* __restrict__ top_idx, const float* __restrict__ top_gate,
    const int* __restrict__ offsets, int* __restrict__ cursors,
    int* __restrict__ tok_list, float* __restrict__ gate_list) {
    const int t = blockIdx.x * 256 + threadIdx.x;
    if (t >= T_TOK) return;
#pragma unroll
    for (int j = 0; j < 2; ++j) {
        const int e = top_idx[2 * t + j];
        const int pos = atomicAdd(&cursors[e], 1);
        const int slot = offsets[e] + pos;
        tok_list[slot] = t;
        gate_list[slot] = top_gate[2 * t + j];
    }
}

// ---------------- GEMM1: h = relu(gather(x) @ W1[e] + b1[e]) -> bf16 ----------
// 256x256, BK=64, 8 waves, 8-phase interleave, counted vmcnt(6), T2 swizzle.
__global__ __launch_bounds__(512, 2) void gemm1_kernel(
    const bf16* __restrict__ xb, const bf16* __restrict__ W1t,
    const float* __restrict__ b1, const int* __restrict__ tok_list,
    const int* __restrict__ offsets, bf16* __restrict__ hbuf) {
    __shared__ bf16 Ak0_0[256 * 32], Ak1_0[256 * 32];
    __shared__ bf16 Bk0_0[256 * 32], Bk1_0[256 * 32];
    __shared__ bf16 Ak0_1[256 * 32], Ak1_1[256 * 32];
    __shared__ bf16 Bk0_1[256 * 32], Bk1_1[256 * 32];
    __shared__ int toks[256];

    const int NCB = F_DIM / 256;          // 16
    const int per = (NUM_RB * NCB) / 8;   // 144
    const int flat = blockIdx.x;
    const int sw = (flat & 7) * per + (flat >> 3);
    const int rb = sw / NCB, cb = sw % NCB;

    const int row0 = rb * BM;
    const int total = offsets[E_NUM];
    if (row0 >= total) return;
    int e = 0;
#pragma unroll
    for (int i = 1; i < E_NUM; ++i) e += (row0 >= offsets[i]) ? 1 : 0;

    const int tid = threadIdx.x;
    if (tid < 256) toks[tid] = tok_list[row0 + tid];
    __syncthreads();   // drains; vmcnt henceforth counts only stage loads

    const int lane = tid & 63;
    const int w = tid >> 6;
    const int wr = w >> 2, wc = w & 3;
    const int f0 = cb * 256;

    // staging: issue i covers rows i*128 + (tid>>2); dest chunk = tid&3
    // T2 pre-swizzled SOURCE chunk: (tid&3)^((tid>>3)&3)
    const int srow = tid >> 2;
    const int csrc = (tid & 3) ^ ((tid >> 3) & 3);
    int t0 = toks[srow]; if (t0 < 0) t0 = 0;
    int t1 = toks[128 + srow]; if (t1 < 0) t1 = 0;
    const bf16* aP0 = xb + (size_t)t0 * D_DIM + csrc * 8;
    const bf16* aP1 = xb + (size_t)t1 * D_DIM + csrc * 8;
    const bf16* bP0 = W1t + ((size_t)e * F_DIM + f0 + srow) * D_DIM + csrc * 8;
    const bf16* bP1 = W1t + ((size_t)e * F_DIM + f0 + 128 + srow) * D_DIM + csrc * 8;

    const unsigned dO0 = __builtin_amdgcn_readfirstlane(w * 1024);
    const unsigned dO1 = __builtin_amdgcn_readfirstlane(8192 + w * 1024);

    const int fkk = 8 * ((lane >> 4) ^ ((lane >> 1) & 3));

    float4v acc[2][4][4];
#pragma unroll
    for (int h = 0; h < 2; ++h)
#pragma unroll
        for (int m = 0; m < 4; ++m)
#pragma unroll
            for (int n = 0; n < 4; ++n)
#pragma unroll
                for (int r = 0; r < 4; ++r) acc[h][m][n][r] = 0.f;

    auto stageA = [&](bf16* R, int ko) {
        gl_lds16(aP0 + ko, (bf16*)((char*)R + dO0));
        gl_lds16(aP1 + ko, (bf16*)((char*)R + dO1));
    };
    auto stageB = [&](bf16* R, int ko) {
        gl_lds16(bP0 + ko, (bf16*)((char*)R + dO0));
        gl_lds16(bP1 + ko, (bf16*)((char*)R + dO1));
    };

    const int NKT = D_DIM / 64;  // 16
    // prologue: tile0 (4 halves) + tile1 (3 halves) = 14 loads
    stageB(Bk0_0, 0); stageA(Ak0_0, 0); stageB(Bk1_0, 32); stageA(Ak1_0, 32);
    stageB(Bk0_1, 64); stageA(Ak0_1, 64); stageB(Bk1_1, 96);
    VM6
    asm volatile("s_barrier" ::: "memory");

    for (int t = 0; t + 3 < NKT; t += 2) {
        const int ko1 = (t + 1) * 64, ko2 = (t + 2) * 64, ko3 = (t + 3) * 64;
        TILE(Ak0_0, Ak1_0, Bk0_0, Bk1_0, Ak1_1, Bk0_0, Ak0_0, Bk1_0,
             true, true, ko1, ko2, VM6)
        TILE(Ak0_1, Ak1_1, Bk0_1, Bk1_1, Ak1_0, Bk0_1, Ak0_1, Bk1_1,
             true, true, ko2, ko3, VM6)
    }
    TILE(Ak0_0, Ak1_0, Bk0_0, Bk1_0, Ak1_1, Bk0_0, Ak0_0, Bk1_0,
         true, false, (NKT - 1) * 64, 0, VM0)
    TILE(Ak0_1, Ak1_1, Bk0_1, Bk1_1, Ak1_0, Bk0_1, Ak0_1, Bk1_1,
         false, false, 0, 0, VMN)

#pragma unroll
    for (int mh = 0; mh < 2; ++mh) {
#pragma unroll
        for (int n = 0; n < 4; ++n) {
            const int gcol = f0 + wc * 64 + n * 16 + (lane & 15);
            const float bias = b1[e * F_DIM + gcol];
#pragma unroll
            for (int m = 0; m < 4; ++m) {
#pragma unroll
                for (int r = 0; r < 4; ++r) {
                    const int grow = row0 + wr * 128 + mh * 64 + m * 16 +
                                     (lane >> 4) * 4 + r;
                    float v = acc[mh][m][n][r] + bias;
                    v = fmaxf(v, 0.f);
                    hbuf[(size_t)grow * F_DIM + gcol] = __float2bfloat16(v);
                }
            }
        }
    }
}

// ---------------- GEMM2: out[tok] += gate * (h @ W2[e] + b2[e]), split-K=2 ----
__global__ __launch_bounds__(512, 2) void gemm2_kernel(
    const bf16* __restrict__ hbuf, const bf16* __restrict__ W2t,
    const float* __restrict__ b2, const int* __restrict__ tok_list,
    const float* __restrict__ gate_list, const int* __restrict__ offsets,
    float* __restrict__ out) {
    __shared__ bf16 Ak0_0[256 * 32], Ak1_0[256 * 32];
    __shared__ bf16 Bk0_0[256 * 32], Bk1_0[256 * 32];
    __shared__ bf16 Ak0_1[256 * 32], Ak1_1[256 * 32];
    __shared__ bf16 Bk0_1[256 * 32], Bk1_1[256 * 32];
    __shared__ int toks[256];
    __shared__ float gates_s[256];

    // nwg = 72*4*2 = 576 (%8==0); (cb,ks)-fastest within XCD chunk
    const int per = (NUM_RB * 8) / 8;     // 72
    const int flat = blockIdx.x;
    const int sw = (flat & 7) * per + (flat >> 3);
    const int rb = sw >> 3;
    const int inner = sw & 7;
    const int cb = inner >> 1, ks = inner & 1;

    const int row0 = rb * BM;
    const int total = offsets[E_NUM];
    if (row0 >= total) return;
    int e = 0;
#pragma unroll
    for (int i = 1; i < E_NUM; ++i) e += (row0 >= offsets[i]) ? 1 : 0;

    const int tid = threadIdx.x;
    if (tid < 256) {
        int t = tok_list[row0 + tid];
        toks[tid] = t;
        gates_s[tid] = (t >= 0) ? gate_list[row0 + tid] : 0.f;
    }
    __syncthreads();

    const int lane = tid & 63;
    const int w = tid >> 6;
    const int wr = w >> 2, wc = w & 3;
    const int d0 = cb * 256;
    const int k0 = ks * (F_DIM / 2);      // 0 or 2048

    const int srow = tid >> 2;
    const int csrc = (tid & 3) ^ ((tid >> 3) & 3);
    const bf16* aP0 = hbuf + (size_t)(row0 + srow) * F_DIM + k0 + csrc * 8;
    const bf16* aP1 = hbuf + (size_t)(row0 + 128 + srow) * F_DIM + k0 + csrc * 8;
    const bf16* bP0 = W2t + ((size_t)e * D_DIM + d0 + srow) * F_DIM + k0 + csrc * 8;
    const bf16* bP1 = W2t + ((size_t)e * D_DIM + d0 + 128 + srow) * F_DIM + k0 + csrc * 8;

    const unsigned dO0 = __builtin_amdgcn_readfirstlane(w * 1024);
    const unsigned dO1 = __builtin_amdgcn_readfirstlane(8192 + w * 1024);

    const int fkk = 8 * ((lane >> 4) ^ ((lane >> 1) & 3));

    float4v acc[2][4][4];
#pragma unroll
    for (int h = 0; h < 2; ++h)
#pragma unroll
        for (int m = 0; m < 4; ++m)
#pragma unroll
            for (int n = 0; n < 4; ++n)
#pragma unroll
                for (int r = 0; r < 4; ++r) acc[h][m][n][r] = 0.f;

    auto stageA = [&](bf16* R, int ko) {
        gl_lds16(aP0 + ko, (bf16*)((char*)R + dO0));
        gl_lds16(aP1 + ko, (bf16*)((char*)R + dO1));
    };
    auto stageB = [&](bf16* R, int ko) {
        gl_lds16(bP0 + ko, (bf16*)((char*)R + dO0));
        gl_lds16(bP1 + ko, (bf16*)((char*)R + dO1));
    };

    const int NKT = (F_DIM / 2) / 64;  // 32
    stageB(Bk0_0, 0); stageA(Ak0_0, 0); stageB(Bk1_0, 32); stageA(Ak1_0, 32);
    stageB(Bk0_1, 64); stageA(Ak0_1, 64); stageB(Bk1_1, 96);
    VM6
    asm volatile("s_barrier" ::: "memory");

    for (int t = 0; t + 3 < NKT; t += 2) {
        const int ko1 = (t + 1) * 64, ko2 = (t + 2) * 64, ko3 = (t + 3) * 64;
        TILE(Ak0_0, Ak1_0, Bk0_0, Bk1_0, Ak1_1, Bk0_0, Ak0_0, Bk1_0,
             true, true, ko1, ko2, VM6)
        TILE(Ak0_1, Ak1_1, Bk0_1, Bk1_1, Ak1_0, Bk0_1, Ak0_1, Bk1_1,
             true, true, ko2, ko3, VM6)
    }
    TILE(Ak0_0, Ak1_0, Bk0_0, Bk1_0, Ak1_1, Bk0_0, Ak0_0, Bk1_0,
         true, false, (NKT - 1) * 64, 0, VM0)
    TILE(Ak0_1, Ak1_1, Bk0_1, Bk1_1, Ak1_0, Bk0_1, Ak0_1, Bk1_1,
         false, false, 0, 0, VMN)

#pragma unroll
    for (int mh = 0; mh < 2; ++mh) {
#pragma unroll
        for (int n = 0; n < 4; ++n) {
            const int gcol = d0 + wc * 64 + n * 16 + (lane & 15);
            const float bias = (ks == 0) ? b2[e * D_DIM + gcol] : 0.f;
#pragma unroll
            for (int m = 0; m < 4; ++m) {
#pragma unroll
                for (int r = 0; r < 4; ++r) {
                    const int lrow = wr * 128 + mh * 64 + m * 16 + (lane >> 4) * 4 + r;
                    const int t = toks[lrow];
                    if (t >= 0) {
                        const float v = (acc[mh][m][n][r] + bias) * gates_s[lrow];
                        atomicAdd(&out[(size_t)t * D_DIM + gcol], v);
                    }
                }
            }
        }
    }
}

extern "C" void kernel_launch(void* const* d_in, const int* in_sizes, int n_in,
                              void* d_out, int out_size, void* d_ws, size_t ws_size,
                              hipStream_t stream) {
    const float* x = (const float*)d_in[0];
    const float* Wg = (const float*)d_in[1];
    const float* bg = (const float*)d_in[2];
    const float* W1 = (const float*)d_in[3];
    const float* b1 = (const float*)d_in[4];
    const float* W2 = (const float*)d_in[5];
    const float* b2 = (const float*)d_in[6];
    float* out = (float*)d_out;

    char* ws = (char*)d_ws;
    int* counts = (int*)(ws + 0);       // 8 ints
    int* cursors = (int*)(ws + 32);     // 8 ints
    int* offsets = (int*)(ws + 64);     // 9 ints
    int* top_idx = (int*)(ws + 256);                 // T*2 ints = 65536 B
    float* top_gate = (float*)(ws + 65792);          // 65536 B
    int* tok_list = (int*)(ws + 131328);             // MAX_ROWS*4 = 73728 B
    float* gate_list = (float*)(ws + 205056);        // 73728 B
    size_t off = 278784;                              // 256-aligned
    bf16* xb = (bf16*)(ws + off);
    off += (size_t)T_TOK * D_DIM * 2;
    bf16* W1t = (bf16*)(ws + off);
    off += (size_t)E_NUM * D_DIM * F_DIM * 2;
    bf16* W2t = (bf16*)(ws + off);
    off += (size_t)E_NUM * D_DIM * F_DIM * 2;
    bf16* hbuf = (bf16*)(ws + off);

    hipMemsetAsync(d_out, 0, (size_t)T_TOK * D_DIM * sizeof(float), stream);
    hipMemsetAsync(ws, 0, 64, stream);                       // counts + cursors
    hipMemsetAsync(tok_list, 0xFF, (size_t)MAX_ROWS * 4, stream);  // -1 sentinels

    xcvt_kernel<<<T_TOK * D_DIM / 4 / 256, 256, 0, stream>>>(x, xb);
    transpose_cvt<<<dim3(F_DIM / 64, D_DIM / 64, E_NUM), dim3(256), 0, stream>>>(
        W1, W1t, D_DIM, F_DIM);
    transpose_cvt<<<dim3(D_DIM / 64, F_DIM / 64, E_NUM), dim3(256), 0, stream>>>(
        W2, W2t, F_DIM, D_DIM);
    router_kernel<<<T_TOK / 4, 256, 0, stream>>>(x, Wg, bg, top_idx, top_gate, counts);
    offsets_kernel<<<1, 64, 0, stream>>>(counts, offsets);
    scatter_kernel<<<T_TOK / 256, 256, 0, stream>>>(top_idx, top_gate, offsets, cursors,
                                                    tok_list, gate_list);
    gemm1_kernel<<<NUM_RB * (F_DIM / 256), 512, 0, stream>>>(xb, W1t, b1, tok_list,
                                                             offsets, hbuf);
    gemm2_kernel<<<NUM_RB * (D_DIM / 256) * 2, 512, 0, stream>>>(hbuf, W2t, b2, tok_list,
                                                                 gate_list, offsets, out);
}

// Round 8
// 962.424 us; speedup vs baseline: 1.0005x; 1.0005x over previous
//
#include <hip/hip_runtime.h>
#include <hip/hip_bf16.h>

#define T_TOK 8192
#define D_DIM 1024
#define F_DIM 4096
#define E_NUM 8
#define BM 256
#define MAX_ROWS (2 * T_TOK + E_NUM * BM)   // 18432
#define NUM_RB (MAX_ROWS / BM)              // 72

typedef __hip_bfloat16 bf16;
using bf16x8  = __attribute__((ext_vector_type(8))) __bf16;
using float4v = __attribute__((ext_vector_type(4))) float;

// async global->LDS, 16B per lane; dest = wave-uniform base + lane*16
__device__ inline void gl_lds16(const bf16* g, bf16* l) {
    __builtin_amdgcn_global_load_lds(
        (const __attribute__((address_space(1))) void*)g,
        (__attribute__((address_space(3))) void*)l, 16, 0, 0);
}

// ---- 8-phase template pieces (m201 port) ----
#define RD_A(REG, MH)                                                         \
    _Pragma("unroll") for (int m_ = 0; m_ < 4; ++m_)                          \
        af[m_] = *(const bf16x8*)&(REG)[(wr * 128 + (MH) * 64 + m_ * 16 +     \
                                         (lane & 15)) * 32 + fkk];
#define RD_B(REG)                                                             \
    _Pragma("unroll") for (int n_ = 0; n_ < 4; ++n_)                          \
        bfr[n_] = *(const bf16x8*)&(REG)[(wc * 64 + n_ * 16 +                 \
                                          (lane & 15)) * 32 + fkk];
#define BAR1()                                                                \
    asm volatile("s_barrier" ::: "memory");                                   \
    asm volatile("s_waitcnt lgkmcnt(0)" ::: "memory");                        \
    __builtin_amdgcn_sched_barrier(0);
#define MFMA16(MH)                                                            \
    __builtin_amdgcn_s_setprio(1);                                            \
    _Pragma("unroll") for (int m_ = 0; m_ < 4; ++m_)                          \
        _Pragma("unroll") for (int n_ = 0; n_ < 4; ++n_)                      \
            acc[MH][m_][n_] = __builtin_amdgcn_mfma_f32_16x16x32_bf16(        \
                af[m_], bfr[n_], acc[MH][m_][n_], 0, 0, 0);                   \
    __builtin_amdgcn_s_setprio(0);                                            \
    asm volatile("s_barrier" ::: "memory");
#define VM6 asm volatile("s_waitcnt vmcnt(6)" ::: "memory");
#define VM0 asm volatile("s_waitcnt vmcnt(0)" ::: "memory");
#define VMN

// One K-tile (BK=64) = 4 phases. Stages: P1 -> Ak1(t+1); P2/P3/P4 ->
// Bk0/Ak0/Bk1 of (t+2). Each region staged one barrier after its last read.
#define TILE(AK0, AK1, BK0, BK1, SAK1T1, SBK0T2, SAK0T2, SBK1T2, D1, D2, KO1, KO2, BVM) \
  { bf16x8 af[4], bfr[4];                                                     \
    RD_A(AK0, 0) RD_B(BK0)                                                    \
    if (D1) { stageA(SAK1T1, (KO1) + 32); }                                   \
    BAR1() MFMA16(0)                                                          \
    RD_A(AK0, 1)                                                              \
    if (D2) { stageB(SBK0T2, (KO2)); }                                        \
    BAR1() MFMA16(1)                                                          \
    RD_A(AK1, 0) RD_B(BK1)                                                    \
    if (D2) { stageA(SAK0T2, (KO2)); }                                        \
    BAR1() MFMA16(0)                                                          \
    RD_A(AK1, 1)                                                              \
    if (D2) { stageB(SBK1T2, (KO2) + 32); }                                   \
    BVM BAR1() MFMA16(1)                                                      \
  }

// ---------------- x -> bf16 ----------------
__global__ __launch_bounds__(256) void xcvt_kernel(const float* __restrict__ x,
                                                   bf16* __restrict__ xb) {
    const int i = blockIdx.x * 256 + threadIdx.x;  // over T*D/4
    float4 v = ((const float4*)x)[i];
    bf16 tmp[4];
    tmp[0] = __float2bfloat16(v.x);
    tmp[1] = __float2bfloat16(v.y);
    tmp[2] = __float2bfloat16(v.z);
    tmp[3] = __float2bfloat16(v.w);
    ((ushort4*)xb)[i] = *(const ushort4*)tmp;
}

// ------- transpose+convert: src[e][M][N] f32 -> dst[e][N][M] bf16, 64x64 tiles -------
__global__ __launch_bounds__(256) void transpose_cvt(const float* __restrict__ src,
                                                     bf16* __restrict__ dst,
                                                     int M, int N) {
    __shared__ float tile[64][65];
    const int e = blockIdx.z;
    const float* s = src + (size_t)e * M * N;
    bf16* d = dst + (size_t)e * M * N;
    const int n0 = blockIdx.x * 64, m0 = blockIdx.y * 64;
    const int tx = threadIdx.x & 15, ty = threadIdx.x >> 4;
#pragma unroll
    for (int i = 0; i < 4; ++i) {
        const int r = ty + i * 16;
        const float4 v = *(const float4*)&s[(size_t)(m0 + r) * N + n0 + tx * 4];
        tile[r][tx * 4 + 0] = v.x;
        tile[r][tx * 4 + 1] = v.y;
        tile[r][tx * 4 + 2] = v.z;
        tile[r][tx * 4 + 3] = v.w;
    }
    __syncthreads();
#pragma unroll
    for (int i = 0; i < 4; ++i) {
        const int nc = ty + i * 16;
        bf16 o[4];
#pragma unroll
        for (int j = 0; j < 4; ++j) o[j] = __float2bfloat16(tile[tx * 4 + j][nc]);
        *(ushort4*)&d[(size_t)(n0 + nc) * M + m0 + tx * 4] = *(const ushort4*)o;
    }
}

// ---------------- router: logits (fp32), top-2, softmax, counts ----------------
__global__ __launch_bounds__(256) void router_kernel(
    const float* __restrict__ x, const float* __restrict__ Wg,
    const float* __restrict__ bg, int* __restrict__ top_idx,
    float* __restrict__ top_gate, int* __restrict__ counts) {
    __shared__ float wg_s[E_NUM][D_DIM];
    for (int i = threadIdx.x; i < D_DIM * E_NUM; i += 256)
        wg_s[i & 7][i >> 3] = Wg[i];
    __syncthreads();

    const int lane = threadIdx.x & 63;
    const int t = blockIdx.x * 4 + (threadIdx.x >> 6);
    float acc[E_NUM];
#pragma unroll
    for (int e = 0; e < E_NUM; ++e) acc[e] = 0.f;
    const float* xrow = x + (size_t)t * D_DIM;
    for (int d = lane; d < D_DIM; d += 64) {
        const float xv = xrow[d];
#pragma unroll
        for (int e = 0; e < E_NUM; ++e) acc[e] += xv * wg_s[e][d];
    }
#pragma unroll
    for (int off = 32; off > 0; off >>= 1) {
#pragma unroll
        for (int e = 0; e < E_NUM; ++e) acc[e] += __shfl_xor(acc[e], off, 64);
    }
    if (lane == 0) {
        float v[E_NUM];
#pragma unroll
        for (int e = 0; e < E_NUM; ++e) v[e] = acc[e] + bg[e];
        int i0 = 0;
#pragma unroll
        for (int e = 1; e < E_NUM; ++e)
            if (v[e] > v[i0]) i0 = e;
        int i1 = -1;
#pragma unroll
        for (int e = 0; e < E_NUM; ++e) {
            if (e == i0) continue;
            if (i1 < 0 || v[e] > v[i1]) i1 = e;
        }
        const float g0 = 1.f / (1.f + expf(v[i1] - v[i0]));
        top_idx[2 * t] = i0;
        top_idx[2 * t + 1] = i1;
        top_gate[2 * t] = g0;
        top_gate[2 * t + 1] = 1.f - g0;
        atomicAdd(&counts[i0], 1);
        atomicAdd(&counts[i1], 1);
    }
}

// ---------------- padded segment offsets (pad to BM=256) ----------------
__global__ void offsets_kernel(const int* __restrict__ counts, int* __restrict__ offsets) {
    if (threadIdx.x == 0) {
        int off = 0;
#pragma unroll
        for (int e = 0; e < E_NUM; ++e) {
            offsets[e] = off;
            off += (counts[e] + BM - 1) / BM * BM;
        }
        offsets[E_NUM] = off;
    }
}

// ---------------- scatter tokens into expert segments ----------------
__global__ __launch_bounds__(256) void scatter_kernel(
    const int* __restrict__ top_idx, const float* __restrict__ top_gate,
    const int* __restrict__ offsets, int* __restrict__ cursors,
    int* __restrict__ tok_list, float* __restrict__ gate_list) {
    const int t = blockIdx.x * 256 + threadIdx.x;
    if (t >= T_TOK) return;
#pragma unroll
    for (int j = 0; j < 2; ++j) {
        const int e = top_idx[2 * t + j];
        const int pos = atomicAdd(&cursors[e], 1);
        const int slot = offsets[e] + pos;
        tok_list[slot] = t;
        gate_list[slot] = top_gate[2 * t + j];
    }
}

// ---------------- GEMM1: h = relu(gather(x) @ W1[e] + b1[e]) -> bf16 ----------
// 256x256, BK=64, 8 waves, 8-phase interleave, counted vmcnt(6), T2 swizzle.
__global__ __launch_bounds__(512, 2) void gemm1_kernel(
    const bf16* __restrict__ xb, const bf16* __restrict__ W1t,
    const float* __restrict__ b1, const int* __restrict__ tok_list,
    const int* __restrict__ offsets, bf16* __restrict__ hbuf) {
    __shared__ bf16 Ak0_0[256 * 32], Ak1_0[256 * 32];
    __shared__ bf16 Bk0_0[256 * 32], Bk1_0[256 * 32];
    __shared__ bf16 Ak0_1[256 * 32], Ak1_1[256 * 32];
    __shared__ bf16 Bk0_1[256 * 32], Bk1_1[256 * 32];
    __shared__ int toks[256];

    const int NCB = F_DIM / 256;          // 16
    const int per = (NUM_RB * NCB) / 8;   // 144
    const int flat = blockIdx.x;
    const int sw = (flat & 7) * per + (flat >> 3);
    const int rb = sw / NCB, cb = sw % NCB;

    const int row0 = rb * BM;
    const int total = offsets[E_NUM];
    if (row0 >= total) return;
    int e = 0;
#pragma unroll
    for (int i = 1; i < E_NUM; ++i) e += (row0 >= offsets[i]) ? 1 : 0;

    const int tid = threadIdx.x;
    if (tid < 256) toks[tid] = tok_list[row0 + tid];
    __syncthreads();   // drains; vmcnt henceforth counts only stage loads

    const int lane = tid & 63;
    const int w = tid >> 6;
    const int wr = w >> 2, wc = w & 3;
    const int f0 = cb * 256;

    // staging: issue i covers rows i*128 + (tid>>2); dest chunk = tid&3
    // T2 pre-swizzled SOURCE chunk: (tid&3)^((tid>>3)&3)
    const int srow = tid >> 2;
    const int csrc = (tid & 3) ^ ((tid >> 3) & 3);
    int t0 = toks[srow]; if (t0 < 0) t0 = 0;
    int t1 = toks[128 + srow]; if (t1 < 0) t1 = 0;
    const bf16* aP0 = xb + (size_t)t0 * D_DIM + csrc * 8;
    const bf16* aP1 = xb + (size_t)t1 * D_DIM + csrc * 8;
    const bf16* bP0 = W1t + ((size_t)e * F_DIM + f0 + srow) * D_DIM + csrc * 8;
    const bf16* bP1 = W1t + ((size_t)e * F_DIM + f0 + 128 + srow) * D_DIM + csrc * 8;

    const unsigned dO0 = __builtin_amdgcn_readfirstlane(w * 1024);
    const unsigned dO1 = __builtin_amdgcn_readfirstlane(8192 + w * 1024);

    const int fkk = 8 * ((lane >> 4) ^ ((lane >> 1) & 3));

    float4v acc[2][4][4];
#pragma unroll
    for (int h = 0; h < 2; ++h)
#pragma unroll
        for (int m = 0; m < 4; ++m)
#pragma unroll
            for (int n = 0; n < 4; ++n)
#pragma unroll
                for (int r = 0; r < 4; ++r) acc[h][m][n][r] = 0.f;

    auto stageA = [&](bf16* R, int ko) {
        gl_lds16(aP0 + ko, (bf16*)((char*)R + dO0));
        gl_lds16(aP1 + ko, (bf16*)((char*)R + dO1));
    };
    auto stageB = [&](bf16* R, int ko) {
        gl_lds16(bP0 + ko, (bf16*)((char*)R + dO0));
        gl_lds16(bP1 + ko, (bf16*)((char*)R + dO1));
    };

    const int NKT = D_DIM / 64;  // 16
    // prologue: tile0 (4 halves) + tile1 (3 halves) = 14 loads
    stageB(Bk0_0, 0); stageA(Ak0_0, 0); stageB(Bk1_0, 32); stageA(Ak1_0, 32);
    stageB(Bk0_1, 64); stageA(Ak0_1, 64); stageB(Bk1_1, 96);
    VM6
    asm volatile("s_barrier" ::: "memory");

    for (int t = 0; t + 3 < NKT; t += 2) {
        const int ko1 = (t + 1) * 64, ko2 = (t + 2) * 64, ko3 = (t + 3) * 64;
        TILE(Ak0_0, Ak1_0, Bk0_0, Bk1_0, Ak1_1, Bk0_0, Ak0_0, Bk1_0,
             true, true, ko1, ko2, VM6)
        TILE(Ak0_1, Ak1_1, Bk0_1, Bk1_1, Ak1_0, Bk0_1, Ak0_1, Bk1_1,
             true, true, ko2, ko3, VM6)
    }
    TILE(Ak0_0, Ak1_0, Bk0_0, Bk1_0, Ak1_1, Bk0_0, Ak0_0, Bk1_0,
         true, false, (NKT - 1) * 64, 0, VM0)
    TILE(Ak0_1, Ak1_1, Bk0_1, Bk1_1, Ak1_0, Bk0_1, Ak0_1, Bk1_1,
         false, false, 0, 0, VMN)

#pragma unroll
    for (int mh = 0; mh < 2; ++mh) {
#pragma unroll
        for (int n = 0; n < 4; ++n) {
            const int gcol = f0 + wc * 64 + n * 16 + (lane & 15);
            const float bias = b1[e * F_DIM + gcol];
#pragma unroll
            for (int m = 0; m < 4; ++m) {
#pragma unroll
                for (int r = 0; r < 4; ++r) {
                    const int grow = row0 + wr * 128 + mh * 64 + m * 16 +
                                     (lane >> 4) * 4 + r;
                    float v = acc[mh][m][n][r] + bias;
                    v = fmaxf(v, 0.f);
                    hbuf[(size_t)grow * F_DIM + gcol] = __float2bfloat16(v);
                }
            }
        }
    }
}

// ---------------- GEMM2: out[tok] += gate * (h @ W2[e] + b2[e]), split-K=2 ----
__global__ __launch_bounds__(512, 2) void gemm2_kernel(
    const bf16* __restrict__ hbuf, const bf16* __restrict__ W2t,
    const float* __restrict__ b2, const int* __restrict__ tok_list,
    const float* __restrict__ gate_list, const int* __restrict__ offsets,
    float* __restrict__ out) {
    __shared__ bf16 Ak0_0[256 * 32], Ak1_0[256 * 32];
    __shared__ bf16 Bk0_0[256 * 32], Bk1_0[256 * 32];
    __shared__ bf16 Ak0_1[256 * 32], Ak1_1[256 * 32];
    __shared__ bf16 Bk0_1[256 * 32], Bk1_1[256 * 32];
    __shared__ int toks[256];
    __shared__ float gates_s[256];

    // nwg = 72*4*2 = 576 (%8==0); (cb,ks)-fastest within XCD chunk
    const int per = (NUM_RB * 8) / 8;     // 72
    const int flat = blockIdx.x;
    const int sw = (flat & 7) * per + (flat >> 3);
    const int rb = sw >> 3;
    const int inner = sw & 7;
    const int cb = inner >> 1, ks = inner & 1;

    const int row0 = rb * BM;
    const int total = offsets[E_NUM];
    if (row0 >= total) return;
    int e = 0;
#pragma unroll
    for (int i = 1; i < E_NUM; ++i) e += (row0 >= offsets[i]) ? 1 : 0;

    const int tid = threadIdx.x;
    if (tid < 256) {
        int t = tok_list[row0 + tid];
        toks[tid] = t;
        gates_s[tid] = (t >= 0) ? gate_list[row0 + tid] : 0.f;
    }
    __syncthreads();

    const int lane = tid & 63;
    const int w = tid >> 6;
    const int wr = w >> 2, wc = w & 3;
    const int d0 = cb * 256;
    const int k0 = ks * (F_DIM / 2);      // 0 or 2048

    const int srow = tid >> 2;
    const int csrc = (tid & 3) ^ ((tid >> 3) & 3);
    const bf16* aP0 = hbuf + (size_t)(row0 + srow) * F_DIM + k0 + csrc * 8;
    const bf16* aP1 = hbuf + (size_t)(row0 + 128 + srow) * F_DIM + k0 + csrc * 8;
    const bf16* bP0 = W2t + ((size_t)e * D_DIM + d0 + srow) * F_DIM + k0 + csrc * 8;
    const bf16* bP1 = W2t + ((size_t)e * D_DIM + d0 + 128 + srow) * F_DIM + k0 + csrc * 8;

    const unsigned dO0 = __builtin_amdgcn_readfirstlane(w * 1024);
    const unsigned dO1 = __builtin_amdgcn_readfirstlane(8192 + w * 1024);

    const int fkk = 8 * ((lane >> 4) ^ ((lane >> 1) & 3));

    float4v acc[2][4][4];
#pragma unroll
    for (int h = 0; h < 2; ++h)
#pragma unroll
        for (int m = 0; m < 4; ++m)
#pragma unroll
            for (int n = 0; n < 4; ++n)
#pragma unroll
                for (int r = 0; r < 4; ++r) acc[h][m][n][r] = 0.f;

    auto stageA = [&](bf16* R, int ko) {
        gl_lds16(aP0 + ko, (bf16*)((char*)R + dO0));
        gl_lds16(aP1 + ko, (bf16*)((char*)R + dO1));
    };
    auto stageB = [&](bf16* R, int ko) {
        gl_lds16(bP0 + ko, (bf16*)((char*)R + dO0));
        gl_lds16(bP1 + ko, (bf16*)((char*)R + dO1));
    };

    const int NKT = (F_DIM / 2) / 64;  // 32
    stageB(Bk0_0, 0); stageA(Ak0_0, 0); stageB(Bk1_0, 32); stageA(Ak1_0, 32);
    stageB(Bk0_1, 64); stageA(Ak0_1, 64); stageB(Bk1_1, 96);
    VM6
    asm volatile("s_barrier" ::: "memory");

    for (int t = 0; t + 3 < NKT; t += 2) {
        const int ko1 = (t + 1) * 64, ko2 = (t + 2) * 64, ko3 = (t + 3) * 64;
        TILE(Ak0_0, Ak1_0, Bk0_0, Bk1_0, Ak1_1, Bk0_0, Ak0_0, Bk1_0,
             true, true, ko1, ko2, VM6)
        TILE(Ak0_1, Ak1_1, Bk0_1, Bk1_1, Ak1_0, Bk0_1, Ak0_1, Bk1_1,
             true, true, ko2, ko3, VM6)
    }
    TILE(Ak0_0, Ak1_0, Bk0_0, Bk1_0, Ak1_1, Bk0_0, Ak0_0, Bk1_0,
         true, false, (NKT - 1) * 64, 0, VM0)
    TILE(Ak0_1, Ak1_1, Bk0_1, Bk1_1, Ak1_0, Bk0_1, Ak0_1, Bk1_1,
         false, false, 0, 0, VMN)

#pragma unroll
    for (int mh = 0; mh < 2; ++mh) {
#pragma unroll
        for (int n = 0; n < 4; ++n) {
            const int gcol = d0 + wc * 64 + n * 16 + (lane & 15);
            const float bias = (ks == 0) ? b2[e * D_DIM + gcol] : 0.f;
#pragma unroll
            for (int m = 0; m < 4; ++m) {
#pragma unroll
                for (int r = 0; r < 4; ++r) {
                    const int lrow = wr * 128 + mh * 64 + m * 16 + (lane >> 4) * 4 + r;
                    const int t = toks[lrow];
                    if (t >= 0) {
                        const float v = (acc[mh][m][n][r] + bias) * gates_s[lrow];
                        atomicAdd(&out[(size_t)t * D_DIM + gcol], v);
                    }
                }
            }
        }
    }
}

extern "C" void kernel_launch(void* const* d_in, const int* in_sizes, int n_in,
                              void* d_out, int out_size, void* d_ws, size_t ws_size,
                              hipStream_t stream) {
    const float* x = (const float*)d_in[0];
    const float* Wg = (const float*)d_in[1];
    const float* bg = (const float*)d_in[2];
    const float* W1 = (const float*)d_in[3];
    const float* b1 = (const float*)d_in[4];
    const float* W2 = (const float*)d_in[5];
    const float* b2 = (const float*)d_in[6];
    float* out = (float*)d_out;

    char* ws = (char*)d_ws;
    int* counts = (int*)(ws + 0);       // 8 ints
    int* cursors = (int*)(ws + 32);     // 8 ints
    int* offsets = (int*)(ws + 64);     // 9 ints
    int* top_idx = (int*)(ws + 256);                 // T*2 ints = 65536 B
    float* top_gate = (float*)(ws + 65792);          // 65536 B
    int* tok_list = (int*)(ws + 131328);             // MAX_ROWS*4 = 73728 B
    float* gate_list = (float*)(ws + 205056);        // 73728 B
    size_t off = 278784;                              // 256-aligned
    bf16* xb = (bf16*)(ws + off);
    off += (size_t)T_TOK * D_DIM * 2;
    bf16* W1t = (bf16*)(ws + off);
    off += (size_t)E_NUM * D_DIM * F_DIM * 2;
    bf16* W2t = (bf16*)(ws + off);
    off += (size_t)E_NUM * D_DIM * F_DIM * 2;
    bf16* hbuf = (bf16*)(ws + off);

    hipMemsetAsync(d_out, 0, (size_t)T_TOK * D_DIM * sizeof(float), stream);
    hipMemsetAsync(ws, 0, 64, stream);                       // counts + cursors
    hipMemsetAsync(tok_list, 0xFF, (size_t)MAX_ROWS * 4, stream);  // -1 sentinels

    xcvt_kernel<<<T_TOK * D_DIM / 4 / 256, 256, 0, stream>>>(x, xb);
    transpose_cvt<<<dim3(F_DIM / 64, D_DIM / 64, E_NUM), dim3(256), 0, stream>>>(
        W1, W1t, D_DIM, F_DIM);
    transpose_cvt<<<dim3(D_DIM / 64, F_DIM / 64, E_NUM), dim3(256), 0, stream>>>(
        W2, W2t, F_DIM, D_DIM);
    router_kernel<<<T_TOK / 4, 256, 0, stream>>>(x, Wg, bg, top_idx, top_gate, counts);
    offsets_kernel<<<1, 64, 0, stream>>>(counts, offsets);
    scatter_kernel<<<T_TOK / 256, 256, 0, stream>>>(top_idx, top_gate, offsets, cursors,
                                                    tok_list, gate_list);
    gemm1_kernel<<<NUM_RB * (F_DIM / 256), 512, 0, stream>>>(xb, W1t, b1, tok_list,
                                                             offsets, hbuf);
    gemm2_kernel<<<NUM_RB * (D_DIM / 256) * 2, 512, 0, stream>>>(hbuf, W2t, b2, tok_list,
                                                                 gate_list, offsets, out);
}

// Round 9
// 852.962 us; speedup vs baseline: 1.1289x; 1.1283x over previous
//
#include <hip/hip_runtime.h>
#include <hip/hip_bf16.h>

#define T_TOK 8192
#define D_DIM 1024
#define F_DIM 4096
#define E_NUM 8
#define BM 128
#define MAX_ROWS (2 * T_TOK + E_NUM * BM)   // 17408
#define NUM_RB (MAX_ROWS / BM)              // 136

typedef __hip_bfloat16 bf16;
using bf16x8  = __attribute__((ext_vector_type(8))) __bf16;
using float4v = __attribute__((ext_vector_type(4))) float;

// async global->LDS, 16B per lane; dest = uniform base + lane*16
__device__ inline void gl_lds16(const bf16* g, bf16* l) {
    __builtin_amdgcn_global_load_lds(
        (const __attribute__((address_space(1))) void*)g,
        (__attribute__((address_space(3))) void*)l, 16, 0, 0);
}

// ---- R4 control phase (gemm1): counted vmcnt, pinned reads, 2 barriers ----
#define PH1(WAITSTR, CA, CB, DOSTAGE, KST)                                     \
    do {                                                                       \
        asm volatile("s_waitcnt " WAITSTR ::: "memory");                       \
        __builtin_amdgcn_s_barrier();                                          \
        bf16x8 af[4], bfr[4];                                                  \
        _Pragma("unroll")                                                      \
        for (int m_ = 0; m_ < 4; ++m_)                                         \
            af[m_] = *(const bf16x8*)&(CA)[(wrow + m_ * 16 + fr) * 32 + fkk];  \
        _Pragma("unroll")                                                      \
        for (int n_ = 0; n_ < 4; ++n_)                                         \
            bfr[n_] = *(const bf16x8*)&(CB)[(wcol + n_ * 16 + fr) * 32 + fkk]; \
        asm volatile("s_waitcnt lgkmcnt(0)" ::: "memory");                     \
        __builtin_amdgcn_sched_barrier(0);                                     \
        __builtin_amdgcn_s_barrier();                                          \
        if (DOSTAGE) stage(KST, CA, CB);                                       \
        __builtin_amdgcn_s_setprio(1);                                         \
        _Pragma("unroll")                                                      \
        for (int m_ = 0; m_ < 4; ++m_)                                         \
            _Pragma("unroll")                                                  \
            for (int n_ = 0; n_ < 4; ++n_)                                     \
                acc[m_][n_] = __builtin_amdgcn_mfma_f32_16x16x32_bf16(         \
                    af[m_], bfr[n_], acc[m_][n_], 0, 0, 0);                    \
        __builtin_amdgcn_s_setprio(0);                                         \
    } while (0)

// ---- experimental phase (gemm2): 3-buffer rotation, ONE barrier, NO pins.
// vmcnt(4): batch t retired (2-phase lookahead). lgkmcnt(0): prev reads
// drained (normally free - MFMA already consumed them). Stage targets the
// buffer last read at t-1 (distinct from both live buffers). Compiler
// emits fine-grained lgkm interleave of reads and MFMAs.
#define PH3(VMSTR, CA, CB, SA, SB, DOSTAGE)                                    \
    do {                                                                       \
        asm volatile("s_waitcnt " VMSTR " lgkmcnt(0)" ::: "memory");           \
        asm volatile("s_barrier" ::: "memory");                                \
        if (DOSTAGE) stage(SA, SB);                                            \
        bf16x8 af[4], bfr[4];                                                  \
        _Pragma("unroll")                                                      \
        for (int m_ = 0; m_ < 4; ++m_)                                         \
            af[m_] = *(const bf16x8*)&(CA)[(wrow + m_ * 16 + fr) * 32 + fkk];  \
        _Pragma("unroll")                                                      \
        for (int n_ = 0; n_ < 4; ++n_)                                         \
            bfr[n_] = *(const bf16x8*)&(CB)[(wcol + n_ * 16 + fr) * 32 + fkk]; \
        _Pragma("unroll")                                                      \
        for (int m_ = 0; m_ < 4; ++m_)                                         \
            _Pragma("unroll")                                                  \
            for (int n_ = 0; n_ < 4; ++n_)                                     \
                acc[m_][n_] = __builtin_amdgcn_mfma_f32_16x16x32_bf16(         \
                    af[m_], bfr[n_], acc[m_][n_], 0, 0, 0);                    \
    } while (0)

// ---------------- x -> bf16 ----------------
__global__ __launch_bounds__(256) void xcvt_kernel(const float* __restrict__ x,
                                                   bf16* __restrict__ xb) {
    const int i = blockIdx.x * 256 + threadIdx.x;  // over T*D/4
    float4 v = ((const float4*)x)[i];
    bf16 tmp[4];
    tmp[0] = __float2bfloat16(v.x);
    tmp[1] = __float2bfloat16(v.y);
    tmp[2] = __float2bfloat16(v.z);
    tmp[3] = __float2bfloat16(v.w);
    ((ushort4*)xb)[i] = *(const ushort4*)tmp;
}

// ------- transpose+convert: src[e][M][N] f32 -> dst[e][N][M] bf16, 64x64 tiles -------
__global__ __launch_bounds__(256) void transpose_cvt(const float* __restrict__ src,
                                                     bf16* __restrict__ dst,
                                                     int M, int N) {
    __shared__ float tile[64][65];
    const int e = blockIdx.z;
    const float* s = src + (size_t)e * M * N;
    bf16* d = dst + (size_t)e * M * N;
    const int n0 = blockIdx.x * 64, m0 = blockIdx.y * 64;
    const int tx = threadIdx.x & 15, ty = threadIdx.x >> 4;
#pragma unroll
    for (int i = 0; i < 4; ++i) {
        const int r = ty + i * 16;
        const float4 v = *(const float4*)&s[(size_t)(m0 + r) * N + n0 + tx * 4];
        tile[r][tx * 4 + 0] = v.x;
        tile[r][tx * 4 + 1] = v.y;
        tile[r][tx * 4 + 2] = v.z;
        tile[r][tx * 4 + 3] = v.w;
    }
    __syncthreads();
#pragma unroll
    for (int i = 0; i < 4; ++i) {
        const int nc = ty + i * 16;
        bf16 o[4];
#pragma unroll
        for (int j = 0; j < 4; ++j) o[j] = __float2bfloat16(tile[tx * 4 + j][nc]);
        *(ushort4*)&d[(size_t)(n0 + nc) * M + m0 + tx * 4] = *(const ushort4*)o;
    }
}

// ---------------- router: logits (fp32), top-2, softmax, counts ----------------
__global__ __launch_bounds__(256) void router_kernel(
    const float* __restrict__ x, const float* __restrict__ Wg,
    const float* __restrict__ bg, int* __restrict__ top_idx,
    float* __restrict__ top_gate, int* __restrict__ counts) {
    __shared__ float wg_s[E_NUM][D_DIM];
    for (int i = threadIdx.x; i < D_DIM * E_NUM; i += 256)
        wg_s[i & 7][i >> 3] = Wg[i];
    __syncthreads();

    const int lane = threadIdx.x & 63;
    const int t = blockIdx.x * 4 + (threadIdx.x >> 6);
    float acc[E_NUM];
#pragma unroll
    for (int e = 0; e < E_NUM; ++e) acc[e] = 0.f;
    const float* xrow = x + (size_t)t * D_DIM;
    for (int d = lane; d < D_DIM; d += 64) {
        const float xv = xrow[d];
#pragma unroll
        for (int e = 0; e < E_NUM; ++e) acc[e] += xv * wg_s[e][d];
    }
#pragma unroll
    for (int off = 32; off > 0; off >>= 1) {
#pragma unroll
        for (int e = 0; e < E_NUM; ++e) acc[e] += __shfl_xor(acc[e], off, 64);
    }
    if (lane == 0) {
        float v[E_NUM];
#pragma unroll
        for (int e = 0; e < E_NUM; ++e) v[e] = acc[e] + bg[e];
        int i0 = 0;
#pragma unroll
        for (int e = 1; e < E_NUM; ++e)
            if (v[e] > v[i0]) i0 = e;
        int i1 = -1;
#pragma unroll
        for (int e = 0; e < E_NUM; ++e) {
            if (e == i0) continue;
            if (i1 < 0 || v[e] > v[i1]) i1 = e;
        }
        const float g0 = 1.f / (1.f + expf(v[i1] - v[i0]));
        top_idx[2 * t] = i0;
        top_idx[2 * t + 1] = i1;
        top_gate[2 * t] = g0;
        top_gate[2 * t + 1] = 1.f - g0;
        atomicAdd(&counts[i0], 1);
        atomicAdd(&counts[i1], 1);
    }
}

// ---------------- padded segment offsets ----------------
__global__ void offsets_kernel(const int* __restrict__ counts, int* __restrict__ offsets) {
    if (threadIdx.x == 0) {
        int off = 0;
#pragma unroll
        for (int e = 0; e < E_NUM; ++e) {
            offsets[e] = off;
            off += (counts[e] + BM - 1) / BM * BM;
        }
        offsets[E_NUM] = off;
    }
}

// ---------------- scatter tokens into expert segments ----------------
__global__ __launch_bounds__(256) void scatter_kernel(
    const int* __restrict__ top_idx, const float* __restrict__ top_gate,
    const int* __restrict__ offsets, int* __restrict__ cursors,
    int* __restrict__ tok_list, float* __restrict__ gate_list) {
    const int t = blockIdx.x * 256 + threadIdx.x;
    if (t >= T_TOK) return;
#pragma unroll
    for (int j = 0; j < 2; ++j) {
        const int e = top_idx[2 * t + j];
        const int pos = atomicAdd(&cursors[e], 1);
        const int slot = offsets[e] + pos;
        tok_list[slot] = t;
        gate_list[slot] = top_gate[2 * t + j];
    }
}

// ---------------- GEMM1 (R4 control): 128², 2-buf counted vmcnt, pinned ----
__global__ __launch_bounds__(256, 4) void gemm1_kernel(
    const bf16* __restrict__ xb, const bf16* __restrict__ W1t,
    const float* __restrict__ b1, const int* __restrict__ tok_list,
    const int* __restrict__ offsets, bf16* __restrict__ hbuf) {
    __shared__ bf16 As0[BM * 32];
    __shared__ bf16 As1[BM * 32];
    __shared__ bf16 Bs0[BM * 32];
    __shared__ bf16 Bs1[BM * 32];
    __shared__ int toks[BM];

    const int NCB = F_DIM / 128;          // 32
    const int per = (NUM_RB * NCB) / 8;   // 544
    const int flat = blockIdx.x;
    const int sw = (flat & 7) * per + (flat >> 3);
    const int rb = sw / NCB, cb = sw % NCB;

    const int row0 = rb * BM;
    const int total = offsets[E_NUM];
    if (row0 >= total) return;
    int e = 0;
#pragma unroll
    for (int i = 1; i < E_NUM; ++i) e += (row0 >= offsets[i]) ? 1 : 0;

    const int tid = threadIdx.x;
    if (tid < BM) toks[tid] = tok_list[row0 + tid];
    __syncthreads();   // full drain: vmcnt henceforth counts only stage loads

    const int lane = tid & 63;
    const int w = tid >> 6;
    const int f0 = cb * 128;

    const int r0 = w * 16 + (lane >> 2);
    const int r1 = 64 + w * 16 + (lane >> 2);
    const int c16 = (lane & 3) ^ ((lane >> 3) & 3);
    int t0 = toks[r0]; if (t0 < 0) t0 = 0;
    int t1 = toks[r1]; if (t1 < 0) t1 = 0;
    const bf16* aP0 = xb + (size_t)t0 * D_DIM + c16 * 8;
    const bf16* aP1 = xb + (size_t)t1 * D_DIM + c16 * 8;
    const bf16* bP0 = W1t + ((size_t)e * F_DIM + f0 + r0) * D_DIM + c16 * 8;
    const bf16* bP1 = W1t + ((size_t)e * F_DIM + f0 + r1) * D_DIM + c16 * 8;

    const unsigned dO0 = __builtin_amdgcn_readfirstlane(w * 1024);
    const unsigned dO1 = __builtin_amdgcn_readfirstlane(4096 + w * 1024);

    const int wrow = (w >> 1) * 64, wcol = (w & 1) * 64;
    const int fr = lane & 15;
    const int fkk = 8 * ((lane >> 4) ^ ((lane >> 1) & 3));

    float4v acc[4][4];
#pragma unroll
    for (int m = 0; m < 4; ++m)
#pragma unroll
        for (int n = 0; n < 4; ++n)
#pragma unroll
            for (int r = 0; r < 4; ++r) acc[m][n][r] = 0.f;

    auto stage = [&](int kt, bf16* A, bf16* B) {
        const int ko = kt * 32;
        gl_lds16(aP0 + ko, (bf16*)((char*)A + dO0));
        gl_lds16(aP1 + ko, (bf16*)((char*)A + dO1));
        gl_lds16(bP0 + ko, (bf16*)((char*)B + dO0));
        gl_lds16(bP1 + ko, (bf16*)((char*)B + dO1));
    };

    const int NKT = D_DIM / 32;  // 32
    stage(0, As0, Bs0);
    stage(1, As1, Bs1);
    for (int kt = 0; kt < NKT - 2; kt += 2) {
        PH1("vmcnt(4)", As0, Bs0, true, kt + 2);
        PH1("vmcnt(4)", As1, Bs1, true, kt + 3);
    }
    PH1("vmcnt(4)", As0, Bs0, false, 0);
    PH1("vmcnt(0)", As1, Bs1, false, 0);

#pragma unroll
    for (int n = 0; n < 4; ++n) {
        const int gcol = f0 + wcol + n * 16 + fr;
        const float bias = b1[e * F_DIM + gcol];
#pragma unroll
        for (int m = 0; m < 4; ++m) {
#pragma unroll
            for (int r = 0; r < 4; ++r) {
                const int grow = row0 + wrow + m * 16 + (lane >> 4) * 4 + r;
                float v = acc[m][n][r] + bias;
                v = fmaxf(v, 0.f);
                hbuf[(size_t)grow * F_DIM + gcol] = __float2bfloat16(v);
            }
        }
    }
}

// ---------------- GEMM2 (experiment): 3-buf rotation, 1 barrier, no pins ----
__global__ __launch_bounds__(256, 3) void gemm2_kernel(
    const bf16* __restrict__ hbuf, const bf16* __restrict__ W2t,
    const float* __restrict__ b2, const int* __restrict__ tok_list,
    const float* __restrict__ gate_list, const int* __restrict__ offsets,
    float* __restrict__ out) {
    __shared__ bf16 As0[BM * 32];
    __shared__ bf16 As1[BM * 32];
    __shared__ bf16 As2[BM * 32];
    __shared__ bf16 Bs0[BM * 32];
    __shared__ bf16 Bs1[BM * 32];
    __shared__ bf16 Bs2[BM * 32];
    __shared__ int toks[BM];
    __shared__ float gates_s[BM];

    const int NCB = D_DIM / 128;          // 8
    const int per = (NUM_RB * NCB) / 8;   // 136
    const int flat = blockIdx.x;
    const int sw = (flat & 7) * per + (flat >> 3);
    const int rb = sw / NCB, cb = sw % NCB;

    const int row0 = rb * BM;
    const int total = offsets[E_NUM];
    if (row0 >= total) return;
    int e = 0;
#pragma unroll
    for (int i = 1; i < E_NUM; ++i) e += (row0 >= offsets[i]) ? 1 : 0;

    const int tid = threadIdx.x;
    if (tid < BM) {
        int t = tok_list[row0 + tid];
        toks[tid] = t;
        gates_s[tid] = (t >= 0) ? gate_list[row0 + tid] : 0.f;
    }
    __syncthreads();

    const int lane = tid & 63;
    const int w = tid >> 6;
    const int d0 = cb * 128;

    const int r0 = w * 16 + (lane >> 2);
    const int r1 = 64 + w * 16 + (lane >> 2);
    const int c16 = (lane & 3) ^ ((lane >> 3) & 3);
    const bf16* aP0 = hbuf + (size_t)(row0 + r0) * F_DIM + c16 * 8;
    const bf16* aP1 = hbuf + (size_t)(row0 + r1) * F_DIM + c16 * 8;
    const bf16* bP0 = W2t + ((size_t)e * D_DIM + d0 + r0) * F_DIM + c16 * 8;
    const bf16* bP1 = W2t + ((size_t)e * D_DIM + d0 + r1) * F_DIM + c16 * 8;

    const unsigned dO0 = __builtin_amdgcn_readfirstlane(w * 1024);
    const unsigned dO1 = __builtin_amdgcn_readfirstlane(4096 + w * 1024);

    const int wrow = (w >> 1) * 64, wcol = (w & 1) * 64;
    const int fr = lane & 15;
    const int fkk = 8 * ((lane >> 4) ^ ((lane >> 1) & 3));

    float4v acc[4][4];
#pragma unroll
    for (int m = 0; m < 4; ++m)
#pragma unroll
        for (int n = 0; n < 4; ++n)
#pragma unroll
            for (int r = 0; r < 4; ++r) acc[m][n][r] = 0.f;

    // sequential stager: each call stages the next K-step (32 cols) in order
    auto stage = [&](bf16* A, bf16* B) {
        gl_lds16(aP0, (bf16*)((char*)A + dO0));
        gl_lds16(aP1, (bf16*)((char*)A + dO1));
        gl_lds16(bP0, (bf16*)((char*)B + dO0));
        gl_lds16(bP1, (bf16*)((char*)B + dO1));
        aP0 += 32; aP1 += 32; bP0 += 32; bP1 += 32;
    };

    const int NKT = F_DIM / 32;  // 128; phases t use buf t%3, stage t+2
    stage(As0, Bs0);
    stage(As1, Bs1);
    for (int kt = 0; kt < NKT - 2; kt += 3) {   // kt = 0,3,...,123: phases kt..kt+2
        PH3("vmcnt(4)", As0, Bs0, As2, Bs2, true);
        PH3("vmcnt(4)", As1, Bs1, As0, Bs0, true);
        PH3("vmcnt(4)", As2, Bs2, As1, Bs1, true);
    }
    PH3("vmcnt(4)", As0, Bs0, As0, Bs0, false);  // phase 126
    PH3("vmcnt(0)", As1, Bs1, As1, Bs1, false);  // phase 127

#pragma unroll
    for (int n = 0; n < 4; ++n) {
        const int gcol = d0 + wcol + n * 16 + fr;
        const float bias = b2[e * D_DIM + gcol];
#pragma unroll
        for (int m = 0; m < 4; ++m) {
#pragma unroll
            for (int r = 0; r < 4; ++r) {
                const int lrow = wrow + m * 16 + (lane >> 4) * 4 + r;
                const int t = toks[lrow];
                if (t >= 0) {
                    const float v = (acc[m][n][r] + bias) * gates_s[lrow];
                    atomicAdd(&out[(size_t)t * D_DIM + gcol], v);
                }
            }
        }
    }
}

extern "C" void kernel_launch(void* const* d_in, const int* in_sizes, int n_in,
                              void* d_out, int out_size, void* d_ws, size_t ws_size,
                              hipStream_t stream) {
    const float* x = (const float*)d_in[0];
    const float* Wg = (const float*)d_in[1];
    const float* bg = (const float*)d_in[2];
    const float* W1 = (const float*)d_in[3];
    const float* b1 = (const float*)d_in[4];
    const float* W2 = (const float*)d_in[5];
    const float* b2 = (const float*)d_in[6];
    float* out = (float*)d_out;

    char* ws = (char*)d_ws;
    int* counts = (int*)(ws + 0);       // 8 ints
    int* cursors = (int*)(ws + 32);     // 8 ints
    int* offsets = (int*)(ws + 64);     // 9 ints
    int* top_idx = (int*)(ws + 256);                     // T*2 ints
    float* top_gate = (float*)(ws + 256 + 65536);        // T*2 floats
    int* tok_list = (int*)(ws + 256 + 2 * 65536);        // MAX_ROWS ints
    float* gate_list = (float*)(ws + 256 + 2 * 65536 + 69632);
    size_t off = 256 + 2 * 65536 + 2 * 69632;            // 270592, 256-aligned
    bf16* xb = (bf16*)(ws + off);
    off += (size_t)T_TOK * D_DIM * 2;
    bf16* W1t = (bf16*)(ws + off);
    off += (size_t)E_NUM * D_DIM * F_DIM * 2;
    bf16* W2t = (bf16*)(ws + off);
    off += (size_t)E_NUM * D_DIM * F_DIM * 2;
    bf16* hbuf = (bf16*)(ws + off);

    hipMemsetAsync(d_out, 0, (size_t)T_TOK * D_DIM * sizeof(float), stream);
    hipMemsetAsync(ws, 0, 64, stream);                       // counts + cursors
    hipMemsetAsync(tok_list, 0xFF, (size_t)MAX_ROWS * 4, stream);  // -1 sentinels

    xcvt_kernel<<<T_TOK * D_DIM / 4 / 256, 256, 0, stream>>>(x, xb);
    transpose_cvt<<<dim3(F_DIM / 64, D_DIM / 64, E_NUM), dim3(256), 0, stream>>>(
        W1, W1t, D_DIM, F_DIM);
    transpose_cvt<<<dim3(D_DIM / 64, F_DIM / 64, E_NUM), dim3(256), 0, stream>>>(
        W2, W2t, F_DIM, D_DIM);
    router_kernel<<<T_TOK / 4, 256, 0, stream>>>(x, Wg, bg, top_idx, top_gate, counts);
    offsets_kernel<<<1, 64, 0, stream>>>(counts, offsets);
    scatter_kernel<<<T_TOK / 256, 256, 0, stream>>>(top_idx, top_gate, offsets, cursors,
                                                    tok_list, gate_list);
    gemm1_kernel<<<NUM_RB * (F_DIM / 128), 256, 0, stream>>>(xb, W1t, b1, tok_list,
                                                             offsets, hbuf);
    gemm2_kernel<<<NUM_RB * (D_DIM / 128), 256, 0, stream>>>(hbuf, W2t, b2, tok_list,
                                                             gate_list, offsets, out);
}